// Round 2
// baseline (448.094 us; speedup 1.0000x reference)
//
#include <hip/hip_runtime.h>
#include <math.h>

#define NB 4
#define NL 256
#define ND 256
#define NP 32
#define NH 8
#define NHD 32

static constexpr float SCALE = 0.17677669529663687f; // HD^-0.5

// ws layout (float offsets)
#define OFF_W2Q 0                      // 128*256
#define OFF_BQ2 (128 * 256)            // 256
#define OFF_K (OFF_BQ2 + 256)          // NB*NH*NL*NHD = 262144
#define OFF_V (OFF_K + NB * NH * NL * NHD)

// ---------------------------------------------------------------------------
// Kernel 0: W2Q = (w2 @ wq) * scale  (128x256);  BQ2 = (b2@wq + bq)*scale
// ---------------------------------------------------------------------------
__global__ __launch_bounds__(256) void prep_kernel(
    const float* __restrict__ w2, const float* __restrict__ b2,
    const float* __restrict__ wq, const float* __restrict__ bq,
    float* __restrict__ ws) {
  int c = blockIdx.x;
  int j = threadIdx.x;
  if (c < 128) {
    __shared__ float row[256];
    row[j] = w2[c * 256 + j];
    __syncthreads();
    float acc = 0.f;
#pragma unroll 8
    for (int e = 0; e < 256; ++e) acc = fmaf(row[e], wq[e * 256 + j], acc);
    ws[OFF_W2Q + c * 256 + j] = acc * SCALE;
  } else {
    float acc = bq[j];
    for (int e = 0; e < 256; ++e) acc = fmaf(b2[e], wq[e * 256 + j], acc);
    ws[OFF_BQ2 + j] = acc * SCALE;
  }
}

// ---------------------------------------------------------------------------
// Kernel 1: K/V projections, head-transposed layout K[b][h][l][d]
// ---------------------------------------------------------------------------
__global__ __launch_bounds__(256) void kv_kernel(
    const float* __restrict__ ehr, const float* __restrict__ wk,
    const float* __restrict__ bk, const float* __restrict__ wv,
    const float* __restrict__ bv, float* __restrict__ ws) {
  int row = blockIdx.x;  // b*NL + l
  int t = threadIdx.x;
  __shared__ float re[256];
  re[t] = ehr[(size_t)row * 256 + t];
  __syncthreads();
  float aK = bk[t], aV = bv[t];
#pragma unroll 4
  for (int c = 0; c < 256; ++c) {
    float e = re[c];
    aK = fmaf(e, wk[c * 256 + t], aK);
    aV = fmaf(e, wv[c * 256 + t], aV);
  }
  int b = row >> 8, l = row & 255;
  int h = t >> 5, d = t & 31;
  size_t o = (((size_t)(b * NH + h)) * NL + l) * NHD + d;
  ws[OFF_K + o] = aK;
  ws[OFF_V + o] = aV;
}

// ---------------------------------------------------------------------------
// Kernel 2: fused time-MLP + q + attention per (b,p,h). Thread = query row.
// Writes ctx into d_out laid out (b,p,l, h*32+d).
// ---------------------------------------------------------------------------
__global__ __launch_bounds__(256) void attn_kernel(
    const float* __restrict__ ehr_times, const float* __restrict__ itv,
    const float* __restrict__ w1, const float* __restrict__ b1,
    const float* __restrict__ ws, float* __restrict__ out) {
  extern __shared__ float smem[];
  float* Kt = smem;            // 8192  [k][d]
  float* Vt = Kt + 8192;       // 8192  [k][d]
  float* Wq = Vt + 8192;       // 4096  [c][j]  (W2Q head slice, scale folded)
  float* w1i = Wq + 4096;      // 512   [c][4] = {w1_0c, w1_1c, w1_2c, b1_c}
  float* bq2h = w1i + 512;     // 32
  float* bias_s = bq2h + 32;   // 256

  int bid = blockIdx.x;  // b*NP*NH + p*NH + h
  int b = bid >> 8;
  int rem = bid & 255;
  int p = rem >> 3;
  int h = rem & 7;
  int t = threadIdx.x;

  const float4* Kg4 = (const float4*)(ws + OFF_K + (size_t)(b * NH + h) * NL * NHD);
  const float4* Vg4 = (const float4*)(ws + OFF_V + (size_t)(b * NH + h) * NL * NHD);
  float4* Kt4 = (float4*)Kt;
  float4* Vt4 = (float4*)Vt;
#pragma unroll
  for (int i = 0; i < 8; ++i) {       // 8 * 256 threads * 4 floats = 8192
    Kt4[i * 256 + t] = Kg4[i * 256 + t];
    Vt4[i * 256 + t] = Vg4[i * 256 + t];
  }
#pragma unroll
  for (int i = 0; i < 16; ++i) {
    int flat = i * 256 + t;  // c*32 + j
    Wq[flat] = ws[OFF_W2Q + (flat >> 5) * 256 + h * NHD + (flat & 31)];
  }
#pragma unroll
  for (int i = 0; i < 2; ++i) {
    int flat = i * 256 + t;  // c*4 + r
    int c = flat >> 2, r = flat & 3;
    w1i[flat] = (r < 3) ? w1[r * 128 + c] : b1[c];
  }
  if (t < 32) bq2h[t] = ws[OFF_BQ2 + h * NHD + t];

  float tl = ehr_times[b * NL + t];
  float st = itv[(b * NP + p) * 2 + 0];
  float en = itv[(b * NP + p) * 2 + 1];
  float center = 0.5f * (st + en);
  bool valid = (tl >= st) && (tl <= en);
  bias_s[t] = valid ? -fabsf(tl - center) : -1.0e30f;
  __syncthreads();

  // ---- q for row t: h_c = gelu(tf . w1[:,c] + b1[c]); q = h @ W2Qh + bq2h
  float dsv = tl - st;
  float dev = en - tl;
  float sg = 1.f / (1.f + __expf(-dsv * dev));

  float q[NHD];
  {
    const float4* bq4 = (const float4*)bq2h;
#pragma unroll
    for (int i = 0; i < 8; ++i) {
      float4 v = bq4[i];
      q[4 * i + 0] = v.x; q[4 * i + 1] = v.y; q[4 * i + 2] = v.z; q[4 * i + 3] = v.w;
    }
  }
  const float4* w14 = (const float4*)w1i;
  const float4* Wq4 = (const float4*)Wq;
#pragma unroll 2
  for (int c = 0; c < 128; ++c) {
    float4 w = w14[c];
    float x = fmaf(dsv, w.x, fmaf(dev, w.y, fmaf(sg, w.z, w.w)));
    float g = 0.5f * x * (1.f + erff(x * 0.70710678118654752f));
#pragma unroll
    for (int i = 0; i < 8; ++i) {
      float4 wv = Wq4[c * 8 + i];
      q[4 * i + 0] = fmaf(g, wv.x, q[4 * i + 0]);
      q[4 * i + 1] = fmaf(g, wv.y, q[4 * i + 1]);
      q[4 * i + 2] = fmaf(g, wv.z, q[4 * i + 2]);
      q[4 * i + 3] = fmaf(g, wv.w, q[4 * i + 3]);
    }
  }

  // ---- single-pass softmax + PV (scores bounded small, no max needed)
  float ctx[NHD];
#pragma unroll
  for (int i = 0; i < NHD; ++i) ctx[i] = 0.f;
  float Z = 0.f;
  const float4* K4 = (const float4*)Kt;
  const float4* V4 = (const float4*)Vt;
#pragma unroll 2
  for (int k = 0; k < NL; ++k) {
    float s = bias_s[k];
    float dot = 0.f;
#pragma unroll
    for (int i = 0; i < 8; ++i) {
      float4 kv = K4[k * 8 + i];
      dot = fmaf(q[4 * i + 0], kv.x, dot);
      dot = fmaf(q[4 * i + 1], kv.y, dot);
      dot = fmaf(q[4 * i + 2], kv.z, dot);
      dot = fmaf(q[4 * i + 3], kv.w, dot);
    }
    float e = __expf(s + dot);
    Z += e;
#pragma unroll
    for (int i = 0; i < 8; ++i) {
      float4 vv = V4[k * 8 + i];
      ctx[4 * i + 0] = fmaf(e, vv.x, ctx[4 * i + 0]);
      ctx[4 * i + 1] = fmaf(e, vv.y, ctx[4 * i + 1]);
      ctx[4 * i + 2] = fmaf(e, vv.z, ctx[4 * i + 2]);
      ctx[4 * i + 3] = fmaf(e, vv.w, ctx[4 * i + 3]);
    }
  }
  float rz = 1.f / Z;
  float4* O = (float4*)(out + (((size_t)(b * NP + p) * NL + t) * ND + h * NHD));
#pragma unroll
  for (int i = 0; i < 8; ++i) {
    O[i] = make_float4(ctx[4 * i + 0] * rz, ctx[4 * i + 1] * rz,
                       ctx[4 * i + 2] * rz, ctx[4 * i + 3] * rz);
  }
}

// ---------------------------------------------------------------------------
// Kernel 3: in-place output projection  out_row = ctx_row @ wo + bo
// block = 64 rows x 256 cols; A staged transposed (stride 65) in LDS.
// ---------------------------------------------------------------------------
__global__ __launch_bounds__(256) void oproj_kernel(
    const float* __restrict__ wo, const float* __restrict__ bo,
    float* __restrict__ out) {
  extern __shared__ float smem[];
  float* At = smem;          // 256*65 = 16640  At[c][r] = A[r][c]
  float* Bt = At + 16640;    // 32*256          Bt[kk][j]

  int bid = blockIdx.x;
  int t = threadIdx.x;
  int r0 = bid * 64;

  // stage A^T (padded stride 65: conflict-free writes, 2-way broadcast reads)
#pragma unroll 8
  for (int i = 0; i < 64; ++i) {
    At[t * 65 + i] = out[(size_t)(r0 + i) * 256 + t];
  }

  float acc[64];
#pragma unroll
  for (int i = 0; i < 64; ++i) acc[i] = 0.f;
  int rg = t >> 5;   // 0..7 -> rows rg*8..rg*8+7
  int cg = t & 31;   // 0..31 -> cols cg*8..cg*8+7

  for (int kt = 0; kt < 8; ++kt) {
    __syncthreads();  // A staged (first iter) / prev Bt consumed
#pragma unroll
    for (int i = 0; i < 32; ++i) {
      Bt[i * 256 + t] = wo[(size_t)(kt * 32 + i) * 256 + t];
    }
    __syncthreads();
#pragma unroll 4
    for (int kk = 0; kk < 32; ++kk) {
      int krow = kt * 32 + kk;
      float a[8];
#pragma unroll
      for (int i = 0; i < 8; ++i) a[i] = At[krow * 65 + rg * 8 + i];
      const float4* B4 = (const float4*)(Bt + kk * 256 + cg * 8);
      float4 b0 = B4[0], b1v = B4[1];
      float bb[8] = {b0.x, b0.y, b0.z, b0.w, b1v.x, b1v.y, b1v.z, b1v.w};
#pragma unroll
      for (int i = 0; i < 8; ++i)
#pragma unroll
        for (int j = 0; j < 8; ++j)
          acc[i * 8 + j] = fmaf(a[i], bb[j], acc[i * 8 + j]);
    }
  }

#pragma unroll
  for (int i = 0; i < 8; ++i) {
    size_t r = r0 + rg * 8 + i;
    float4 o0 = make_float4(acc[i * 8 + 0] + bo[cg * 8 + 0],
                            acc[i * 8 + 1] + bo[cg * 8 + 1],
                            acc[i * 8 + 2] + bo[cg * 8 + 2],
                            acc[i * 8 + 3] + bo[cg * 8 + 3]);
    float4 o1 = make_float4(acc[i * 8 + 4] + bo[cg * 8 + 4],
                            acc[i * 8 + 5] + bo[cg * 8 + 5],
                            acc[i * 8 + 6] + bo[cg * 8 + 6],
                            acc[i * 8 + 7] + bo[cg * 8 + 7]);
    float4* Orow = (float4*)(out + r * 256 + cg * 8);
    Orow[0] = o0;
    Orow[1] = o1;
  }
}

// ---------------------------------------------------------------------------
extern "C" void kernel_launch(void* const* d_in, const int* in_sizes, int n_in,
                              void* d_out, int out_size, void* d_ws, size_t ws_size,
                              hipStream_t stream) {
  const float* ehr = (const float*)d_in[0];
  const float* ehr_times = (const float*)d_in[1];
  const float* itv = (const float*)d_in[2];
  const float* w1 = (const float*)d_in[3];
  const float* b1 = (const float*)d_in[4];
  const float* w2 = (const float*)d_in[5];
  const float* b2 = (const float*)d_in[6];
  const float* wq = (const float*)d_in[7];
  const float* bq = (const float*)d_in[8];
  const float* wk = (const float*)d_in[9];
  const float* bk = (const float*)d_in[10];
  const float* wv = (const float*)d_in[11];
  const float* bv = (const float*)d_in[12];
  const float* wo = (const float*)d_in[13];
  const float* bo = (const float*)d_in[14];
  float* out = (float*)d_out;
  float* ws = (float*)d_ws;

  // allow >64KB dynamic LDS
  (void)hipFuncSetAttribute((const void*)attn_kernel,
                            hipFuncAttributeMaxDynamicSharedMemorySize, 160 * 1024);
  (void)hipFuncSetAttribute((const void*)oproj_kernel,
                            hipFuncAttributeMaxDynamicSharedMemorySize, 160 * 1024);

  prep_kernel<<<129, 256, 0, stream>>>(w2, b2, wq, bq, ws);
  kv_kernel<<<NB * NL, 256, 0, stream>>>(ehr, wk, bk, wv, bv, ws);

  size_t attn_lds = (size_t)(8192 + 8192 + 4096 + 512 + 32 + 256) * sizeof(float);
  attn_kernel<<<NB * NP * NH, 256, attn_lds, stream>>>(ehr_times, itv, w1, b1, ws, out);

  size_t oproj_lds = (size_t)(16640 + 32 * 256) * sizeof(float);
  oproj_kernel<<<(NB * NP * NL) / 64, 256, oproj_lds, stream>>>(wo, bo, out);
}

// Round 3
// 216.179 us; speedup vs baseline: 2.0728x; 2.0728x over previous
//
#include <hip/hip_runtime.h>
#include <math.h>

#define NB 4
#define NL 256
#define ND 256
#define NP 32
#define NH 8
#define NHD 32

// HD^-0.5 * log2(e)  (log2e folded so softmax exp becomes exp2)
static constexpr float SCALE = 0.17677669529663687f * 1.4426950408889634f;
static constexpr float LOG2E = 1.4426950408889634f;

// ws layout (float offsets)
#define OFF_W2Q 0                      // 128*256
#define OFF_BQ2 (128 * 256)            // 256
#define OFF_K (OFF_BQ2 + 256)          // NB*NH*NL*NHD = 262144
#define OFF_V (OFF_K + NB * NH * NL * NHD)

typedef __bf16 bf16x8 __attribute__((ext_vector_type(8)));
typedef float f32x4 __attribute__((ext_vector_type(4)));

// byte offset of (row, 16B-chunk) in a [N][32]bf16 tile, XOR-swizzled so that
// both frag reads (row=base+lane&15, chunk=lane>>4) and row-wise writes are
// <=2-way bank conflicted. 8 slots of 16B per 128B segment (2 rows).
__device__ __forceinline__ int fq(int row, int chunk) {
  int slot = ((row & 1) * 4 + chunk) ^ ((row >> 1) & 7);
  return (row >> 1) * 128 + slot * 16;
}

__device__ __forceinline__ unsigned short bf16b(float x) {
  return __builtin_bit_cast(unsigned short, (__bf16)x);
}

// ---------------------------------------------------------------------------
// Kernel 0: W2Q = (w2 @ wq) * SCALE  (128x256);  BQ2 = (b2@wq + bq)*SCALE
// ---------------------------------------------------------------------------
__global__ __launch_bounds__(256) void prep_kernel(
    const float* __restrict__ w2, const float* __restrict__ b2,
    const float* __restrict__ wq, const float* __restrict__ bq,
    float* __restrict__ ws) {
  int c = blockIdx.x;
  int j = threadIdx.x;
  if (c < 128) {
    __shared__ float row[256];
    row[j] = w2[c * 256 + j];
    __syncthreads();
    float acc = 0.f;
#pragma unroll 8
    for (int e = 0; e < 256; ++e) acc = fmaf(row[e], wq[e * 256 + j], acc);
    ws[OFF_W2Q + c * 256 + j] = acc * SCALE;
  } else {
    float acc = bq[j];
    for (int e = 0; e < 256; ++e) acc = fmaf(b2[e], wq[e * 256 + j], acc);
    ws[OFF_BQ2 + j] = acc * SCALE;
  }
}

// ---------------------------------------------------------------------------
// Kernel 1: K/V projections, head-transposed layout K[b][h][l][d] (fp32)
// ---------------------------------------------------------------------------
__global__ __launch_bounds__(256) void kv_kernel(
    const float* __restrict__ ehr, const float* __restrict__ wk,
    const float* __restrict__ bk, const float* __restrict__ wv,
    const float* __restrict__ bv, float* __restrict__ ws) {
  int row = blockIdx.x;  // b*NL + l
  int t = threadIdx.x;
  __shared__ float re[256];
  re[t] = ehr[(size_t)row * 256 + t];
  __syncthreads();
  float aK = bk[t], aV = bv[t];
#pragma unroll 4
  for (int c = 0; c < 256; ++c) {
    float e = re[c];
    aK = fmaf(e, wk[c * 256 + t], aK);
    aV = fmaf(e, wv[c * 256 + t], aV);
  }
  int b = row >> 8, l = row & 255;
  int h = t >> 5, d = t & 31;
  size_t o = (((size_t)(b * NH + h)) * NL + l) * NHD + d;
  ws[OFF_K + o] = aK;
  ws[OFF_V + o] = aV;
}

// ---------------------------------------------------------------------------
// Kernel 2: fused time-MLP + q + MFMA attention per (b,p,h).
// 4 waves; wave w owns query rows 64w..64w+63. bf16 MFMA 16x16x32.
// LDS byte offsets:
#define QB_OFF 0            // [256][32] bf16 swizzled, 16384
#define KB_OFF 16384        // [256][32] bf16 swizzled, 16384
#define VT_OFF 32768        // [32][264] bf16 (V^T, 528B row stride), 16896
#define BIAS_OFF 49664      // 256 f32 (pre-multiplied by log2e), 1024
#define UN_OFF 50688        // union: phase1 Wq[128][32] f32 (16384)
                            //        phase3 P: per-wave [64][32] bf16 swz (4x4096)
#define W1I_OFF (UN_OFF + 16384)   // 512 f32
#define BQ2H_OFF (W1I_OFF + 2048)  // 32 f32
#define ATTN_LDS (BQ2H_OFF + 128)
// ---------------------------------------------------------------------------
__global__ __launch_bounds__(256) void attn_kernel(
    const float* __restrict__ ehr_times, const float* __restrict__ itv,
    const float* __restrict__ w1, const float* __restrict__ b1,
    const float* __restrict__ ws, float* __restrict__ out) {
  extern __shared__ char sm[];
  float* Wq = (float*)(sm + UN_OFF);
  float* w1i = (float*)(sm + W1I_OFF);
  float* bq2h = (float*)(sm + BQ2H_OFF);
  float* bias_s = (float*)(sm + BIAS_OFF);

  int bid = blockIdx.x;  // b*NP*NH + p*NH + h
  int b = bid >> 8;
  int rem = bid & 255;
  int p = rem >> 3;
  int h = rem & 7;
  int t = threadIdx.x;

  // ---- stage K (swizzled bf16) and V^T (bf16) ----
  {
    const float4* Kg4 = (const float4*)(ws + OFF_K + (size_t)(b * NH + h) * NL * NHD) + t * 8;
    float krow[32];
#pragma unroll
    for (int i = 0; i < 8; ++i) ((float4*)krow)[i] = Kg4[i];
#pragma unroll
    for (int c = 0; c < 4; ++c) {
      bf16x8 pk;
#pragma unroll
      for (int j = 0; j < 8; ++j) pk[j] = (__bf16)krow[c * 8 + j];
      *(bf16x8*)(sm + KB_OFF + fq(t, c)) = pk;
    }
    const float4* Vg4 = (const float4*)(ws + OFF_V + (size_t)(b * NH + h) * NL * NHD) + t * 8;
    float vrow[32];
#pragma unroll
    for (int i = 0; i < 8; ++i) ((float4*)vrow)[i] = Vg4[i];
    int vb = VT_OFF + ((t >> 3) << 4) + ((t & 7) << 1);
#pragma unroll
    for (int d = 0; d < 32; ++d)
      *(unsigned short*)(sm + vb + d * 528) = bf16b(vrow[d]);
  }
  // ---- stage Wq (W2Q head slice), w1 interleaved, bq2h, bias ----
#pragma unroll
  for (int i = 0; i < 16; ++i) {
    int flat = i * 256 + t;  // c*32 + j
    Wq[flat] = ws[OFF_W2Q + (flat >> 5) * 256 + h * NHD + (flat & 31)];
  }
#pragma unroll
  for (int i = 0; i < 2; ++i) {
    int flat = i * 256 + t;  // c*4 + r
    int c = flat >> 2, r = flat & 3;
    w1i[flat] = (r < 3) ? w1[r * 128 + c] : b1[c];
  }
  if (t < 32) bq2h[t] = ws[OFF_BQ2 + h * NHD + t];

  float tl = ehr_times[b * NL + t];
  float st = itv[(b * NP + p) * 2 + 0];
  float en = itv[(b * NP + p) * 2 + 1];
  float center = 0.5f * (st + en);
  bool valid = (tl >= st) && (tl <= en);
  bias_s[t] = valid ? -fabsf(tl - center) * LOG2E : -1.0e30f;
  __syncthreads();

  // ---- q for row t (fp32), then store bf16 swizzled ----
  float dsv = tl - st;
  float dev = en - tl;
  float sg = 1.f / (1.f + __expf(-dsv * dev));
  float q[NHD];
  {
    const float4* bq4 = (const float4*)bq2h;
#pragma unroll
    for (int i = 0; i < 8; ++i) {
      float4 v = bq4[i];
      q[4 * i + 0] = v.x; q[4 * i + 1] = v.y; q[4 * i + 2] = v.z; q[4 * i + 3] = v.w;
    }
  }
  const float4* w14 = (const float4*)w1i;
  const float4* Wq4 = (const float4*)Wq;
#pragma unroll 2
  for (int c = 0; c < 128; ++c) {
    float4 w = w14[c];
    float x = fmaf(dsv, w.x, fmaf(dev, w.y, fmaf(sg, w.z, w.w)));
    float g = 0.5f * x * (1.f + erff(x * 0.70710678118654752f));
#pragma unroll
    for (int i = 0; i < 8; ++i) {
      float4 wv = Wq4[c * 8 + i];
      q[4 * i + 0] = fmaf(g, wv.x, q[4 * i + 0]);
      q[4 * i + 1] = fmaf(g, wv.y, q[4 * i + 1]);
      q[4 * i + 2] = fmaf(g, wv.z, q[4 * i + 2]);
      q[4 * i + 3] = fmaf(g, wv.w, q[4 * i + 3]);
    }
  }
#pragma unroll
  for (int c = 0; c < 4; ++c) {
    bf16x8 pk;
#pragma unroll
    for (int j = 0; j < 8; ++j) pk[j] = (__bf16)q[c * 8 + j];
    *(bf16x8*)(sm + QB_OFF + fq(t, c)) = pk;
  }
  __syncthreads();

  // ---- MFMA flash loop: wave w owns rows 64w..64w+63 ----
  int lane = t & 63;
  int w = t >> 6;
  int lo = lane & 15;   // A-row / B-col / D-col index
  int hi = lane >> 4;   // k-chunk / D-row-group
  int R0 = w * 64;
  int PB = UN_OFF + w * 4096;  // per-wave P buffer [64][32] bf16 swizzled

  bf16x8 aq[4];
#pragma unroll
  for (int r = 0; r < 4; ++r)
    aq[r] = *(const bf16x8*)(sm + QB_OFF + fq(R0 + r * 16 + lo, hi));

  f32x4 acc[4][2];
#pragma unroll
  for (int r = 0; r < 4; ++r)
#pragma unroll
    for (int c = 0; c < 2; ++c) acc[r][c] = (f32x4){0.f, 0.f, 0.f, 0.f};
  float zac[4][4];
#pragma unroll
  for (int r = 0; r < 4; ++r)
#pragma unroll
    for (int i = 0; i < 4; ++i) zac[r][i] = 0.f;

  for (int kb = 0; kb < 8; ++kb) {
    bf16x8 bk0 = *(const bf16x8*)(sm + KB_OFF + fq(kb * 32 + lo, hi));
    bf16x8 bk1 = *(const bf16x8*)(sm + KB_OFF + fq(kb * 32 + 16 + lo, hi));
    float bias0 = bias_s[kb * 32 + lo];
    float bias1 = bias_s[kb * 32 + 16 + lo];
#pragma unroll
    for (int r = 0; r < 4; ++r) {
      f32x4 z4 = (f32x4){0.f, 0.f, 0.f, 0.f};
      f32x4 s0 = __builtin_amdgcn_mfma_f32_16x16x32_bf16(aq[r], bk0, z4, 0, 0, 0);
      f32x4 s1 = __builtin_amdgcn_mfma_f32_16x16x32_bf16(aq[r], bk1, z4, 0, 0, 0);
#pragma unroll
      for (int i = 0; i < 4; ++i) {
        float e0 = exp2f(s0[i] + bias0);
        float e1 = exp2f(s1[i] + bias1);
        zac[r][i] += e0 + e1;
        int prow = r * 16 + hi * 4 + i;
        *(unsigned short*)(sm + PB + fq(prow, lo >> 3) + (lo & 7) * 2) = bf16b(e0);
        *(unsigned short*)(sm + PB + fq(prow, 2 + (lo >> 3)) + (lo & 7) * 2) = bf16b(e1);
      }
    }
    __syncthreads();
    bf16x8 vb0 = *(const bf16x8*)(sm + VT_OFF + lo * 528 + (kb * 4 + hi) * 16);
    bf16x8 vb1 = *(const bf16x8*)(sm + VT_OFF + (16 + lo) * 528 + (kb * 4 + hi) * 16);
#pragma unroll
    for (int r = 0; r < 4; ++r) {
      bf16x8 pa = *(const bf16x8*)(sm + PB + fq(r * 16 + lo, hi));
      acc[r][0] = __builtin_amdgcn_mfma_f32_16x16x32_bf16(pa, vb0, acc[r][0], 0, 0, 0);
      acc[r][1] = __builtin_amdgcn_mfma_f32_16x16x32_bf16(pa, vb1, acc[r][1], 0, 0, 0);
    }
    __syncthreads();
  }

  // ---- Z reduce across the 16 lanes sharing rows (lo varies) ----
#pragma unroll
  for (int r = 0; r < 4; ++r)
#pragma unroll
    for (int i = 0; i < 4; ++i) {
      float z = zac[r][i];
      z += __shfl_xor(z, 1);
      z += __shfl_xor(z, 2);
      z += __shfl_xor(z, 4);
      z += __shfl_xor(z, 8);
      zac[r][i] = 1.f / z;
    }

  // ---- write ctx into out (b,p,row,h*32+d) ----
  size_t obase = ((size_t)(b * NP + p) * NL) * 256 + h * NHD;
#pragma unroll
  for (int r = 0; r < 4; ++r) {
    int qr = R0 + r * 16 + hi * 4;
#pragma unroll
    for (int c = 0; c < 2; ++c)
#pragma unroll
      for (int i = 0; i < 4; ++i)
        out[obase + (size_t)(qr + i) * 256 + c * 16 + lo] = acc[r][c][i] * zac[r][i];
  }
}

// ---------------------------------------------------------------------------
// Kernel 3: in-place output projection  out_row = ctx_row @ wo + bo
// ---------------------------------------------------------------------------
__global__ __launch_bounds__(256) void oproj_kernel(
    const float* __restrict__ wo, const float* __restrict__ bo,
    float* __restrict__ out) {
  extern __shared__ float smem[];
  float* At = smem;          // 256*65 = 16640  At[c][r] = A[r][c]
  float* Bt = At + 16640;    // 32*256          Bt[kk][j]

  int bid = blockIdx.x;
  int t = threadIdx.x;
  int r0 = bid * 64;

#pragma unroll 8
  for (int i = 0; i < 64; ++i) {
    At[t * 65 + i] = out[(size_t)(r0 + i) * 256 + t];
  }

  float acc[64];
#pragma unroll
  for (int i = 0; i < 64; ++i) acc[i] = 0.f;
  int rg = t >> 5;
  int cg = t & 31;

  for (int kt = 0; kt < 8; ++kt) {
    __syncthreads();
#pragma unroll
    for (int i = 0; i < 32; ++i) {
      Bt[i * 256 + t] = wo[(size_t)(kt * 32 + i) * 256 + t];
    }
    __syncthreads();
#pragma unroll 4
    for (int kk = 0; kk < 32; ++kk) {
      int krow = kt * 32 + kk;
      float a[8];
#pragma unroll
      for (int i = 0; i < 8; ++i) a[i] = At[krow * 65 + rg * 8 + i];
      const float4* B4 = (const float4*)(Bt + kk * 256 + cg * 8);
      float4 b0 = B4[0], b1v = B4[1];
      float bb[8] = {b0.x, b0.y, b0.z, b0.w, b1v.x, b1v.y, b1v.z, b1v.w};
#pragma unroll
      for (int i = 0; i < 8; ++i)
#pragma unroll
        for (int j = 0; j < 8; ++j)
          acc[i * 8 + j] = fmaf(a[i], bb[j], acc[i * 8 + j]);
    }
  }

#pragma unroll
  for (int i = 0; i < 8; ++i) {
    size_t r = r0 + rg * 8 + i;
    float4 o0 = make_float4(acc[i * 8 + 0] + bo[cg * 8 + 0],
                            acc[i * 8 + 1] + bo[cg * 8 + 1],
                            acc[i * 8 + 2] + bo[cg * 8 + 2],
                            acc[i * 8 + 3] + bo[cg * 8 + 3]);
    float4 o1 = make_float4(acc[i * 8 + 4] + bo[cg * 8 + 4],
                            acc[i * 8 + 5] + bo[cg * 8 + 5],
                            acc[i * 8 + 6] + bo[cg * 8 + 6],
                            acc[i * 8 + 7] + bo[cg * 8 + 7]);
    float4* Orow = (float4*)(out + r * 256 + cg * 8);
    Orow[0] = o0;
    Orow[1] = o1;
  }
}

// ---------------------------------------------------------------------------
extern "C" void kernel_launch(void* const* d_in, const int* in_sizes, int n_in,
                              void* d_out, int out_size, void* d_ws, size_t ws_size,
                              hipStream_t stream) {
  const float* ehr = (const float*)d_in[0];
  const float* ehr_times = (const float*)d_in[1];
  const float* itv = (const float*)d_in[2];
  const float* w1 = (const float*)d_in[3];
  const float* b1 = (const float*)d_in[4];
  const float* w2 = (const float*)d_in[5];
  const float* b2 = (const float*)d_in[6];
  const float* wq = (const float*)d_in[7];
  const float* bq = (const float*)d_in[8];
  const float* wk = (const float*)d_in[9];
  const float* bk = (const float*)d_in[10];
  const float* wv = (const float*)d_in[11];
  const float* bv = (const float*)d_in[12];
  const float* wo = (const float*)d_in[13];
  const float* bo = (const float*)d_in[14];
  float* out = (float*)d_out;
  float* ws = (float*)d_ws;

  (void)hipFuncSetAttribute((const void*)attn_kernel,
                            hipFuncAttributeMaxDynamicSharedMemorySize, 160 * 1024);
  (void)hipFuncSetAttribute((const void*)oproj_kernel,
                            hipFuncAttributeMaxDynamicSharedMemorySize, 160 * 1024);

  prep_kernel<<<129, 256, 0, stream>>>(w2, b2, wq, bq, ws);
  kv_kernel<<<NB * NL, 256, 0, stream>>>(ehr, wk, bk, wv, bv, ws);

  attn_kernel<<<NB * NP * NH, 256, ATTN_LDS, stream>>>(ehr_times, itv, w1, b1, ws, out);

  size_t oproj_lds = (size_t)(16640 + 32 * 256) * sizeof(float);
  oproj_kernel<<<(NB * NP * NL) / 64, 256, oproj_lds, stream>>>(wo, bo, out);
}

// Round 4
// 90.197 us; speedup vs baseline: 4.9680x; 2.3967x over previous
//
#include <hip/hip_runtime.h>
#include <math.h>

#define NB 4
#define NL 256
#define NP 32

// HD^-0.5 * log2(e) folded into W2Q/BQ2; bias pre-multiplied by log2(e).
static constexpr float SCALE = 0.17677669529663687f * 1.4426950408889634f;
static constexpr float LOG2E = 1.4426950408889634f;

typedef __bf16 bf16x8 __attribute__((ext_vector_type(8)));
typedef float f32x4 __attribute__((ext_vector_type(4)));
typedef unsigned int u32x4 __attribute__((ext_vector_type(4)));
typedef unsigned int u32x2 __attribute__((ext_vector_type(2)));

// ---- ws byte offsets (total ~1.5 MB) ----
#define WS_W2QT 0                        // [256 j][128 c] bf16 = 65536
#define WS_BQ2  65536                    // 256 f32 = 1024
#define WS_WKT  66560                    // [256 j][256 k] bf16 = 131072
#define WS_WVT  (66560 + 131072)
#define WS_WOT  (66560 + 2 * 131072)
#define WS_KIMG (66560 + 3 * 131072)     // per (b,h): [256 key][32 d] bf16 = 16384; x32
#define WS_VT   (WS_KIMG + 524288)       // per (b,h): [32 d][256 key] bf16 = 16384; x32

__device__ __forceinline__ unsigned short bf16b(float x) {
  return __builtin_bit_cast(unsigned short, (__bf16)x);
}
__device__ __forceinline__ unsigned pack2(float a, float b) {
  return (unsigned)bf16b(a) | ((unsigned)bf16b(b) << 16);
}
// XOR-swizzled byte offset of (row, 16B-chunk) in per-ktblock [N][32]bf16 tiles.
__device__ __forceinline__ int fqs(int row, int chunk, int ktb, int ktbytes) {
  int slot = (((row & 1) << 2) + chunk) ^ ((row >> 1) & 7) ^ (ktb & 7);
  return ktb * ktbytes + (row >> 1) * 128 + slot * 16;
}
__device__ __forceinline__ f32x4 zero4() { return (f32x4){0.f, 0.f, 0.f, 0.f}; }

// ---------------------------------------------------------------------------
// prep: W2QT bf16 (scale+log2e folded), BQ2 f32, and bf16 transposed images
// of wk/wv/wo.  grid = 225 blocks x 256.
// ---------------------------------------------------------------------------
__global__ __launch_bounds__(256) void prep_kernel(
    const float* __restrict__ w2, const float* __restrict__ b2,
    const float* __restrict__ wq, const float* __restrict__ bq,
    const float* __restrict__ wk, const float* __restrict__ wv,
    const float* __restrict__ wo, char* __restrict__ ws) {
  int c = blockIdx.x, j = threadIdx.x;
  if (c < 128) {
    __shared__ float row[256];
    row[j] = w2[c * 256 + j];
    __syncthreads();
    float acc = 0.f;
#pragma unroll 8
    for (int e = 0; e < 256; ++e) acc = fmaf(row[e], wq[e * 256 + j], acc);
    *(unsigned short*)(ws + WS_W2QT + j * 256 + c * 2) = bf16b(acc * SCALE);
  } else if (c == 128) {
    float acc = bq[j];
    for (int e = 0; e < 256; ++e) acc = fmaf(b2[e], wq[e * 256 + j], acc);
    ((float*)(ws + WS_BQ2))[j] = acc * SCALE;
  } else {
    int idx = c - 129;  // 0..95
    const float* src = (idx < 32) ? wk : (idx < 64) ? wv : wo;
    char* dst = ws + WS_WKT + (size_t)(idx >> 5) * 131072;
    int kblk = idx & 31;
    __shared__ float tl[8][257];
#pragma unroll
    for (int r = 0; r < 8; ++r) tl[r][j] = src[(kblk * 8 + r) * 256 + j];
    __syncthreads();
    u32x4 v;
#pragma unroll
    for (int r2 = 0; r2 < 4; ++r2)
      v[r2] = pack2(tl[2 * r2][j], tl[2 * r2 + 1][j]);
    *(u32x4*)(dst + j * 512 + kblk * 16) = v;
  }
}

// ---------------------------------------------------------------------------
// kv: MFMA projections. 64 blocks x 16 ehr rows. Emits KIMG [key][32d] and
// VT [32d][key] bf16 images per (b,h).
// ---------------------------------------------------------------------------
__global__ __launch_bounds__(256) void kv_kernel(
    const float* __restrict__ ehr, const float* __restrict__ bk,
    const float* __restrict__ bv, char* __restrict__ ws) {
  __shared__ __align__(16) char Alds[8192];
  int t = threadIdx.x;
  int R0 = blockIdx.x * 16;
  {
    int row = t >> 4;
#pragma unroll
    for (int u = 0; u < 2; ++u) {
      int c = (t & 15) * 2 + u;  // 16B chunk 0..31
      const float4* s4 = (const float4*)(ehr + (size_t)(R0 + row) * 256 + c * 8);
      float4 x0 = s4[0], x1 = s4[1];
      bf16x8 pk;
      pk[0] = (__bf16)x0.x; pk[1] = (__bf16)x0.y; pk[2] = (__bf16)x0.z; pk[3] = (__bf16)x0.w;
      pk[4] = (__bf16)x1.x; pk[5] = (__bf16)x1.y; pk[6] = (__bf16)x1.z; pk[7] = (__bf16)x1.w;
      *(bf16x8*)(Alds + fqs(row, c & 3, c >> 2, 1024)) = pk;
    }
  }
  __syncthreads();
  int lane = t & 63, w = t >> 6, lo = lane & 15, hi = lane >> 4;
  f32x4 aK[4], aV[4];
#pragma unroll
  for (int nt = 0; nt < 4; ++nt) { aK[nt] = zero4(); aV[nt] = zero4(); }
  const char* wkT = ws + WS_WKT;
  const char* wvT = ws + WS_WVT;
#pragma unroll
  for (int kt = 0; kt < 8; ++kt) {
    bf16x8 af = *(const bf16x8*)(Alds + fqs(lo, hi, kt, 1024));
#pragma unroll
    for (int nt = 0; nt < 4; ++nt) {
      int j = (w * 4 + nt) * 16 + lo;
      bf16x8 bK = *(const bf16x8*)(wkT + j * 512 + (kt * 32 + hi * 8) * 2);
      bf16x8 bV = *(const bf16x8*)(wvT + j * 512 + (kt * 32 + hi * 8) * 2);
      aK[nt] = __builtin_amdgcn_mfma_f32_16x16x32_bf16(af, bK, aK[nt], 0, 0, 0);
      aV[nt] = __builtin_amdgcn_mfma_f32_16x16x32_bf16(af, bV, aV[nt], 0, 0, 0);
    }
  }
  int b = R0 >> 8;
  int l0 = (R0 & 255) + hi * 4;
#pragma unroll
  for (int nt = 0; nt < 4; ++nt) {
    int j = (w * 4 + nt) * 16 + lo;
    int h = j >> 5, d = j & 31;
    float bkj = bk[j], bvj = bv[j];
    char* kb = ws + WS_KIMG + (size_t)(b * 8 + h) * 16384;
#pragma unroll
    for (int i = 0; i < 4; ++i)
      *(unsigned short*)(kb + (l0 + i) * 64 + d * 2) = bf16b(aK[nt][i] + bkj);
    u32x2 vv;
    vv[0] = pack2(aV[nt][0] + bvj, aV[nt][1] + bvj);
    vv[1] = pack2(aV[nt][2] + bvj, aV[nt][3] + bvj);
    *(u32x2*)(ws + WS_VT + (size_t)(b * 8 + h) * 16384 + d * 512 + l0 * 2) = vv;
  }
}

// ---------------------------------------------------------------------------
// attn: block=(b,p,lhalf), 512 thr, wave=head, 128 q-rows/wave.
// S^T = mfma(K, q) so P is lane-local per q-row; P->PV via pack+shfl.
// ctx written bf16 into upper 512B of each output row's fp32 slot.
// ---------------------------------------------------------------------------
__global__ __launch_bounds__(512) void attn_kernel(
    const float* __restrict__ ehr_times, const float* __restrict__ itv,
    const float* __restrict__ w1, const float* __restrict__ b1,
    const char* __restrict__ ws, float* __restrict__ outp) {
  __shared__ __align__(16) char Hlds[32768];
  __shared__ __align__(16) float bias_s[256];
  __shared__ __align__(16) float w1i[512];
  int t = threadIdx.x;
  int bid = blockIdx.x;  // b*64 + p*2 + lh
  int b = bid >> 6, rem = bid & 63, p = rem >> 1, lh = rem & 1;
  {
    int cc = t >> 2, r = t & 3;
    w1i[t] = (r < 3) ? w1[r * 128 + cc] : b1[cc];
  }
  float st = itv[(b * NP + p) * 2 + 0];
  float en = itv[(b * NP + p) * 2 + 1];
  if (t < 256) {
    float tk = ehr_times[b * 256 + t];
    bool valid = (tk >= st) && (tk <= en);
    bias_s[t] = valid ? -fabsf(tk - 0.5f * (st + en)) * LOG2E : -1.0e30f;
  }
  __syncthreads();
  {  // H = gelu(tf @ w1 + b1), bf16, swizzled: thread t -> row t>>2, ktblk t&3
    int lr = t >> 2, ktb = t & 3;
    float tl = ehr_times[b * 256 + lh * 128 + lr];
    float dsv = tl - st, dev = en - tl;
    float sg = 1.f / (1.f + __expf(-dsv * dev));
    const float4* w14 = (const float4*)w1i;
#pragma unroll
    for (int cc = 0; cc < 4; ++cc) {
      bf16x8 pk;
#pragma unroll
      for (int u = 0; u < 8; ++u) {
        float4 wv = w14[ktb * 32 + cc * 8 + u];
        float x = fmaf(dsv, wv.x, fmaf(dev, wv.y, fmaf(sg, wv.z, wv.w)));
        float g = 0.5f * x * (1.f + erff(x * 0.70710678118654752f));
        pk[u] = (__bf16)g;
      }
      *(bf16x8*)(Hlds + fqs(lr, cc, ktb, 8192)) = pk;
    }
  }
  __syncthreads();

  int lane = t & 63, h = t >> 6, lo = lane & 15, hi = lane >> 4;
  int s0 = lo + ((hi & 1) << 5);  // shfl source lanes for 4->8 regroup
  int s1 = s0 + 16;
  bool lohalf = hi < 2;

  // ---- q^T = W2QT_h @ H^T (+BQ2), redistributed to QK B-frags ----
  bf16x8 qb[8];
  {
    bf16x8 aW[2][4];
#pragma unroll
    for (int dt = 0; dt < 2; ++dt)
#pragma unroll
      for (int kt = 0; kt < 4; ++kt)
        aW[dt][kt] = *(const bf16x8*)(ws + WS_W2QT +
                                      (h * 32 + dt * 16 + lo) * 256 + (kt * 32 + hi * 8) * 2);
    const float* BQ2 = (const float*)(ws + WS_BQ2);
    float bqv[2][4];
#pragma unroll
    for (int dt = 0; dt < 2; ++dt)
#pragma unroll
      for (int i = 0; i < 4; ++i) bqv[dt][i] = BQ2[h * 32 + dt * 16 + hi * 4 + i];
#pragma unroll
    for (int r = 0; r < 8; ++r) {
      f32x4 q0 = zero4(), q1 = zero4();
#pragma unroll
      for (int kt = 0; kt < 4; ++kt) {
        bf16x8 bh = *(const bf16x8*)(Hlds + fqs(r * 16 + lo, hi, kt, 8192));
        q0 = __builtin_amdgcn_mfma_f32_16x16x32_bf16(aW[0][kt], bh, q0, 0, 0, 0);
        q1 = __builtin_amdgcn_mfma_f32_16x16x32_bf16(aW[1][kt], bh, q1, 0, 0, 0);
      }
      unsigned A0 = pack2(q0[0] + bqv[0][0], q0[1] + bqv[0][1]);
      unsigned A1 = pack2(q0[2] + bqv[0][2], q0[3] + bqv[0][3]);
      unsigned B0 = pack2(q1[0] + bqv[1][0], q1[1] + bqv[1][1]);
      unsigned B1 = pack2(q1[2] + bqv[1][2], q1[3] + bqv[1][3]);
      unsigned a0 = (unsigned)__shfl((int)A0, s0), a1 = (unsigned)__shfl((int)A1, s0);
      unsigned a2 = (unsigned)__shfl((int)A0, s1), a3 = (unsigned)__shfl((int)A1, s1);
      unsigned c0 = (unsigned)__shfl((int)B0, s0), c1 = (unsigned)__shfl((int)B1, s0);
      unsigned c2 = (unsigned)__shfl((int)B0, s1), c3 = (unsigned)__shfl((int)B1, s1);
      u32x4 qv;
      qv[0] = lohalf ? a0 : c0; qv[1] = lohalf ? a1 : c1;
      qv[2] = lohalf ? a2 : c2; qv[3] = lohalf ? a3 : c3;
      qb[r] = __builtin_bit_cast(bf16x8, qv);
    }
  }

  // ---- flash loop over 8 key-blocks of 32; no LDS, no barriers ----
  f32x4 acc[2][8];
  float z[8];
#pragma unroll
  for (int r = 0; r < 8; ++r) { acc[0][r] = zero4(); acc[1][r] = zero4(); z[r] = 0.f; }
  const char* Kb = ws + WS_KIMG + (size_t)(b * 8 + h) * 16384;
  const char* Vb = ws + WS_VT + (size_t)(b * 8 + h) * 16384;
#pragma unroll 2
  for (int kb = 0; kb < 8; ++kb) {
    bf16x8 kf0 = *(const bf16x8*)(Kb + (kb * 32 + lo) * 64 + hi * 16);
    bf16x8 kf1 = *(const bf16x8*)(Kb + (kb * 32 + 16 + lo) * 64 + hi * 16);
    bf16x8 vf0 = *(const bf16x8*)(Vb + lo * 512 + (kb * 32 + hi * 8) * 2);
    bf16x8 vf1 = *(const bf16x8*)(Vb + (16 + lo) * 512 + (kb * 32 + hi * 8) * 2);
    f32x4 bia0 = *(const f32x4*)(bias_s + kb * 32 + hi * 4);
    f32x4 bia1 = *(const f32x4*)(bias_s + kb * 32 + 16 + hi * 4);
#pragma unroll
    for (int r = 0; r < 8; ++r) {
      f32x4 sc0 = __builtin_amdgcn_mfma_f32_16x16x32_bf16(kf0, qb[r], zero4(), 0, 0, 0);
      f32x4 sc1 = __builtin_amdgcn_mfma_f32_16x16x32_bf16(kf1, qb[r], zero4(), 0, 0, 0);
      float e0 = exp2f(sc0[0] + bia0[0]), e1 = exp2f(sc0[1] + bia0[1]);
      float e2 = exp2f(sc0[2] + bia0[2]), e3 = exp2f(sc0[3] + bia0[3]);
      float f0 = exp2f(sc1[0] + bia1[0]), f1 = exp2f(sc1[1] + bia1[1]);
      float f2 = exp2f(sc1[2] + bia1[2]), f3 = exp2f(sc1[3] + bia1[3]);
      z[r] += ((e0 + e1) + (e2 + e3)) + ((f0 + f1) + (f2 + f3));
      unsigned A0 = pack2(e0, e1), A1 = pack2(e2, e3);
      unsigned B0 = pack2(f0, f1), B1 = pack2(f2, f3);
      unsigned a0 = (unsigned)__shfl((int)A0, s0), a1 = (unsigned)__shfl((int)A1, s0);
      unsigned a2 = (unsigned)__shfl((int)A0, s1), a3 = (unsigned)__shfl((int)A1, s1);
      unsigned c0 = (unsigned)__shfl((int)B0, s0), c1 = (unsigned)__shfl((int)B1, s0);
      unsigned c2 = (unsigned)__shfl((int)B0, s1), c3 = (unsigned)__shfl((int)B1, s1);
      u32x4 pv;
      pv[0] = lohalf ? a0 : c0; pv[1] = lohalf ? a1 : c1;
      pv[2] = lohalf ? a2 : c2; pv[3] = lohalf ? a3 : c3;
      bf16x8 pb = __builtin_bit_cast(bf16x8, pv);
      acc[0][r] = __builtin_amdgcn_mfma_f32_16x16x32_bf16(vf0, pb, acc[0][r], 0, 0, 0);
      acc[1][r] = __builtin_amdgcn_mfma_f32_16x16x32_bf16(vf1, pb, acc[1][r], 0, 0, 0);
    }
  }

  // ---- epilogue: Z-reduce across hi-groups; ctx bf16 -> d_out row upper half
  char* ob = (char*)outp + (size_t)((b * NP + p) * 256 + lh * 128) * 1024;
#pragma unroll
  for (int r = 0; r < 8; ++r) {
    float zz = z[r];
    zz += __shfl_xor(zz, 16);
    zz += __shfl_xor(zz, 32);
    float rz = 1.f / zz;
    char* po = ob + (size_t)(r * 16 + lo) * 1024 + 512 + (h * 32 + hi * 4) * 2;
    u32x2 o0, o1;
    o0[0] = pack2(acc[0][r][0] * rz, acc[0][r][1] * rz);
    o0[1] = pack2(acc[0][r][2] * rz, acc[0][r][3] * rz);
    o1[0] = pack2(acc[1][r][0] * rz, acc[1][r][1] * rz);
    o1[1] = pack2(acc[1][r][2] * rz, acc[1][r][3] * rz);
    *(u32x2*)po = o0;
    *(u32x2*)(po + 32) = o1;  // dt=1 -> +16 cols
  }
}

// ---------------------------------------------------------------------------
// oproj: MFMA, in-place per 64-row block (reads own rows' bf16 ctx, writes
// same rows fp32). B-frags from woT image in L2.
// ---------------------------------------------------------------------------
__global__ __launch_bounds__(256) void oproj_kernel(
    const float* __restrict__ bo, const char* __restrict__ ws,
    float* __restrict__ outp) {
  __shared__ __align__(16) char Alds[32768];
  int t = threadIdx.x;
  int r0 = blockIdx.x * 64;
  {
    int row = t >> 2;
    const char* src = (const char*)outp + (size_t)(r0 + row) * 1024 + 512 + (t & 3) * 128;
#pragma unroll
    for (int u = 0; u < 8; ++u) {
      int c = (t & 3) * 8 + u;
      u32x4 v = *(const u32x4*)(src + u * 16);
      *(u32x4*)(Alds + fqs(row, c & 3, c >> 2, 4096)) = v;
    }
  }
  __syncthreads();
  int lane = t & 63, w = t >> 6, lo = lane & 15, hi = lane >> 4;
  f32x4 acc[4][4];
#pragma unroll
  for (int rt = 0; rt < 4; ++rt)
#pragma unroll
    for (int nt = 0; nt < 4; ++nt) acc[rt][nt] = zero4();
  const char* woT = ws + WS_WOT;
#pragma unroll
  for (int kt = 0; kt < 8; ++kt) {
    bf16x8 af[4];
#pragma unroll
    for (int rt = 0; rt < 4; ++rt)
      af[rt] = *(const bf16x8*)(Alds + fqs(rt * 16 + lo, hi, kt, 4096));
#pragma unroll
    for (int nt = 0; nt < 4; ++nt) {
      int j = (w * 4 + nt) * 16 + lo;
      bf16x8 bf = *(const bf16x8*)(woT + j * 512 + (kt * 32 + hi * 8) * 2);
#pragma unroll
      for (int rt = 0; rt < 4; ++rt)
        acc[rt][nt] = __builtin_amdgcn_mfma_f32_16x16x32_bf16(af[rt], bf, acc[rt][nt], 0, 0, 0);
    }
  }
#pragma unroll
  for (int nt = 0; nt < 4; ++nt) {
    int j = (w * 4 + nt) * 16 + lo;
    float boj = bo[j];
#pragma unroll
    for (int rt = 0; rt < 4; ++rt)
#pragma unroll
      for (int i = 0; i < 4; ++i)
        outp[(size_t)(r0 + rt * 16 + hi * 4 + i) * 256 + j] = acc[rt][nt][i] + boj;
  }
}

// ---------------------------------------------------------------------------
extern "C" void kernel_launch(void* const* d_in, const int* in_sizes, int n_in,
                              void* d_out, int out_size, void* d_ws, size_t ws_size,
                              hipStream_t stream) {
  const float* ehr = (const float*)d_in[0];
  const float* ehr_times = (const float*)d_in[1];
  const float* itv = (const float*)d_in[2];
  const float* w1 = (const float*)d_in[3];
  const float* b1 = (const float*)d_in[4];
  const float* w2 = (const float*)d_in[5];
  const float* b2 = (const float*)d_in[6];
  const float* wq = (const float*)d_in[7];
  const float* bq = (const float*)d_in[8];
  const float* wk = (const float*)d_in[9];
  const float* bk = (const float*)d_in[10];
  const float* wv = (const float*)d_in[11];
  const float* bv = (const float*)d_in[12];
  const float* wo = (const float*)d_in[13];
  const float* bo = (const float*)d_in[14];
  float* out = (float*)d_out;
  char* ws = (char*)d_ws;

  prep_kernel<<<225, 256, 0, stream>>>(w2, b2, wq, bq, wk, wv, wo, ws);
  kv_kernel<<<64, 256, 0, stream>>>(ehr, bk, bv, ws);
  attn_kernel<<<NB * NP * 2, 512, 0, stream>>>(ehr_times, itv, w1, b1, ws, out);
  oproj_kernel<<<512, 256, 0, stream>>>(bo, ws, out);
}

// Round 5
// 85.695 us; speedup vs baseline: 5.2290x; 1.0525x over previous
//
#include <hip/hip_runtime.h>
#include <math.h>

#define NB 4
#define NL 256
#define NP 32

// HD^-0.5 * log2(e) folded into W2Q/BQ2; bias pre-multiplied by log2(e).
static constexpr float SCALE = 0.17677669529663687f * 1.4426950408889634f;
static constexpr float LOG2E = 1.4426950408889634f;

typedef __bf16 bf16x8 __attribute__((ext_vector_type(8)));
typedef float f32x4 __attribute__((ext_vector_type(4)));
typedef float f32x16 __attribute__((ext_vector_type(16)));
typedef unsigned int u32x4 __attribute__((ext_vector_type(4)));
typedef unsigned int u32x2 __attribute__((ext_vector_type(2)));

// ---- ws byte offsets (total ~1.5 MB) ----
#define WS_W2QT 0                        // [256 j][128 c] bf16 = 65536
#define WS_BQ2  65536                    // 256 f32 = 1024
#define WS_WKT  66560                    // [256 j][256 k] bf16 = 131072
#define WS_WVT  (66560 + 131072)
#define WS_WOT  (66560 + 2 * 131072)
#define WS_KIMG (66560 + 3 * 131072)     // per (b,h): [256 key][32 d] bf16 = 16384; x32
#define WS_VT   (WS_KIMG + 524288)       // per (b,h): [32 d][256 key] bf16 = 16384; x32

__device__ __forceinline__ unsigned short bf16b(float x) {
  return __builtin_bit_cast(unsigned short, (__bf16)x);
}
__device__ __forceinline__ unsigned pack2(float a, float b) {
  return (unsigned)bf16b(a) | ((unsigned)bf16b(b) << 16);
}
// v_permlane32_swap_b32: a' = {a.lo, b.lo}, b' = {a.hi, b.hi}
__device__ __forceinline__ void pl32swap(unsigned& a, unsigned& b) {
  asm("v_permlane32_swap_b32 %0, %1" : "+v"(a), "+v"(b));
}
// XOR-swizzled byte offset of (row, 16B-chunk) in per-ktblock [N][32]bf16 tiles.
__device__ __forceinline__ int fqs(int row, int chunk, int ktb, int ktbytes) {
  int slot = (((row & 1) << 2) + chunk) ^ ((row >> 1) & 7) ^ (ktb & 7);
  return ktb * ktbytes + (row >> 1) * 128 + slot * 16;
}
__device__ __forceinline__ f32x4 zero4() { return (f32x4){0.f, 0.f, 0.f, 0.f}; }

// ---------------------------------------------------------------------------
// prep: W2QT bf16 (scale+log2e folded), BQ2 f32, and bf16 transposed images
// of wk/wv/wo.  grid = 225 blocks x 256.
// ---------------------------------------------------------------------------
__global__ __launch_bounds__(256) void prep_kernel(
    const float* __restrict__ w2, const float* __restrict__ b2,
    const float* __restrict__ wq, const float* __restrict__ bq,
    const float* __restrict__ wk, const float* __restrict__ wv,
    const float* __restrict__ wo, char* __restrict__ ws) {
  int c = blockIdx.x, j = threadIdx.x;
  if (c < 128) {
    __shared__ float row[256];
    row[j] = w2[c * 256 + j];
    __syncthreads();
    float acc = 0.f;
#pragma unroll 8
    for (int e = 0; e < 256; ++e) acc = fmaf(row[e], wq[e * 256 + j], acc);
    *(unsigned short*)(ws + WS_W2QT + j * 256 + c * 2) = bf16b(acc * SCALE);
  } else if (c == 128) {
    float acc = bq[j];
    for (int e = 0; e < 256; ++e) acc = fmaf(b2[e], wq[e * 256 + j], acc);
    ((float*)(ws + WS_BQ2))[j] = acc * SCALE;
  } else {
    int idx = c - 129;  // 0..95
    const float* src = (idx < 32) ? wk : (idx < 64) ? wv : wo;
    char* dst = ws + WS_WKT + (size_t)(idx >> 5) * 131072;
    int kblk = idx & 31;
    __shared__ float tl[8][257];
#pragma unroll
    for (int r = 0; r < 8; ++r) tl[r][j] = src[(kblk * 8 + r) * 256 + j];
    __syncthreads();
    u32x4 v;
#pragma unroll
    for (int r2 = 0; r2 < 4; ++r2)
      v[r2] = pack2(tl[2 * r2][j], tl[2 * r2 + 1][j]);
    *(u32x4*)(dst + j * 512 + kblk * 16) = v;
  }
}

// ---------------------------------------------------------------------------
// kv: MFMA projections. 64 blocks x 16 ehr rows. Emits KIMG [key][32d] and
// VT [32d][key] bf16 images per (b,h).
// ---------------------------------------------------------------------------
__global__ __launch_bounds__(256) void kv_kernel(
    const float* __restrict__ ehr, const float* __restrict__ bk,
    const float* __restrict__ bv, char* __restrict__ ws) {
  __shared__ __align__(16) char Alds[8192];
  int t = threadIdx.x;
  int R0 = blockIdx.x * 16;
  {
    int row = t >> 4;
#pragma unroll
    for (int u = 0; u < 2; ++u) {
      int c = (t & 15) * 2 + u;  // 16B chunk 0..31
      const float4* s4 = (const float4*)(ehr + (size_t)(R0 + row) * 256 + c * 8);
      float4 x0 = s4[0], x1 = s4[1];
      bf16x8 pk;
      pk[0] = (__bf16)x0.x; pk[1] = (__bf16)x0.y; pk[2] = (__bf16)x0.z; pk[3] = (__bf16)x0.w;
      pk[4] = (__bf16)x1.x; pk[5] = (__bf16)x1.y; pk[6] = (__bf16)x1.z; pk[7] = (__bf16)x1.w;
      *(bf16x8*)(Alds + fqs(row, c & 3, c >> 2, 1024)) = pk;
    }
  }
  __syncthreads();
  int lane = t & 63, w = t >> 6, lo = lane & 15, hi = lane >> 4;
  f32x4 aK[4], aV[4];
#pragma unroll
  for (int nt = 0; nt < 4; ++nt) { aK[nt] = zero4(); aV[nt] = zero4(); }
  const char* wkT = ws + WS_WKT;
  const char* wvT = ws + WS_WVT;
#pragma unroll
  for (int kt = 0; kt < 8; ++kt) {
    bf16x8 af = *(const bf16x8*)(Alds + fqs(lo, hi, kt, 1024));
#pragma unroll
    for (int nt = 0; nt < 4; ++nt) {
      int j = (w * 4 + nt) * 16 + lo;
      bf16x8 bK = *(const bf16x8*)(wkT + j * 512 + (kt * 32 + hi * 8) * 2);
      bf16x8 bV = *(const bf16x8*)(wvT + j * 512 + (kt * 32 + hi * 8) * 2);
      aK[nt] = __builtin_amdgcn_mfma_f32_16x16x32_bf16(af, bK, aK[nt], 0, 0, 0);
      aV[nt] = __builtin_amdgcn_mfma_f32_16x16x32_bf16(af, bV, aV[nt], 0, 0, 0);
    }
  }
  int b = R0 >> 8;
  int l0 = (R0 & 255) + hi * 4;
#pragma unroll
  for (int nt = 0; nt < 4; ++nt) {
    int j = (w * 4 + nt) * 16 + lo;
    int h = j >> 5, d = j & 31;
    float bkj = bk[j], bvj = bv[j];
    char* kb = ws + WS_KIMG + (size_t)(b * 8 + h) * 16384;
#pragma unroll
    for (int i = 0; i < 4; ++i)
      *(unsigned short*)(kb + (l0 + i) * 64 + d * 2) = bf16b(aK[nt][i] + bkj);
    u32x2 vv;
    vv[0] = pack2(aV[nt][0] + bvj, aV[nt][1] + bvj);
    vv[1] = pack2(aV[nt][2] + bvj, aV[nt][3] + bvj);
    *(u32x2*)(ws + WS_VT + (size_t)(b * 8 + h) * 16384 + d * 512 + l0 * 2) = vv;
  }
}

// ---------------------------------------------------------------------------
// attn v5: block=(b,p,64-row quarter), 512 thr, wave=head, 2 q-tiles of 32.
// 32x32x16 MFMA; bias in C-operand; P/q redistribution via permlane32_swap.
// Zero LDS/barriers in the flash loop.
// ---------------------------------------------------------------------------
__global__ __launch_bounds__(512, 4) void attn_kernel(
    const float* __restrict__ ehr_times, const float* __restrict__ itv,
    const float* __restrict__ w1, const float* __restrict__ b1,
    const char* __restrict__ ws, float* __restrict__ outp) {
  __shared__ __align__(16) char Hlds[16384];  // [64 rows][128 c] bf16, chunk-XOR swz
  __shared__ __align__(16) float bias_s[256];
  __shared__ __align__(16) float w1i[512];
  int t = threadIdx.x;
  int bid = blockIdx.x;  // (b*32+p)*4 + lq
  int b = bid >> 7, p = (bid >> 2) & 31, lq = bid & 3;
  {
    int cc = t >> 2, r = t & 3;
    w1i[t] = (r < 3) ? w1[r * 128 + cc] : b1[cc];
  }
  float st = itv[(b * NP + p) * 2 + 0];
  float en = itv[(b * NP + p) * 2 + 1];
  if (t < 256) {
    float tk = ehr_times[b * 256 + t];
    bool valid = (tk >= st) && (tk <= en);
    bias_s[t] = valid ? -fabsf(tk - 0.5f * (st + en)) * LOG2E : -1.0e30f;
  }
  __syncthreads();
  {  // H = gelu(tf @ w1 + b1) for this block's 64 rows; 16 gelu/thread
    int row = t >> 3;
    float tl = ehr_times[b * 256 + lq * 64 + row];
    float dsv = tl - st, dev = en - tl;
    float sg = 1.f / (1.f + __expf(-dsv * dev));
    const float4* w14 = (const float4*)w1i;
#pragma unroll
    for (int cc = 0; cc < 2; ++cc) {
      int cz = (t & 7) * 2 + cc;  // 16B chunk, c = cz*8..+7
      bf16x8 pk;
#pragma unroll
      for (int u = 0; u < 8; ++u) {
        float4 wv = w14[cz * 8 + u];
        float x = fmaf(dsv, wv.x, fmaf(dev, wv.y, fmaf(sg, wv.z, wv.w)));
        pk[u] = (__bf16)(0.5f * x * (1.f + erff(x * 0.70710678118654752f)));
      }
      *(bf16x8*)(Hlds + row * 256 + ((cz ^ (row & 15)) << 4)) = pk;
    }
  }
  __syncthreads();

  int lane = t & 63, h = t >> 6;
  int cl = lane & 31;  // col within 32-tile
  int hb = lane >> 5;  // half

  // ---- q-build: q^T = W2QT_h @ H^T (+BQ2 via C-init) ----
  u32x4 qbA[2], qbB[2];
  {
    const float* BQ2 = (const float*)(ws + WS_BQ2);
    f32x16 cfrag;
#pragma unroll
    for (int g = 0; g < 4; ++g) {
      f32x4 v = *(const f32x4*)(BQ2 + h * 32 + g * 8 + hb * 4);
      cfrag[4 * g + 0] = v[0]; cfrag[4 * g + 1] = v[1];
      cfrag[4 * g + 2] = v[2]; cfrag[4 * g + 3] = v[3];
    }
    const char* WQ = ws + WS_W2QT + (size_t)(h * 32 + cl) * 256 + hb * 16;
#pragma unroll
    for (int qt = 0; qt < 2; ++qt) {
      f32x16 s = cfrag;
      int hrow = qt * 32 + cl;
#pragma unroll
      for (int ck = 0; ck < 8; ++ck) {
        bf16x8 aW = *(const bf16x8*)(WQ + ck * 32);
        bf16x8 bh = *(const bf16x8*)(Hlds + hrow * 256 +
                                     ((((ck << 1) | hb) ^ (hrow & 15)) << 4));
        s = __builtin_amdgcn_mfma_f32_32x32x16_bf16(aW, bh, s, 0, 0, 0);
      }
      unsigned u0 = pack2(s[0], s[1]), u1 = pack2(s[2], s[3]);
      unsigned u2 = pack2(s[4], s[5]), u3 = pack2(s[6], s[7]);
      unsigned u4 = pack2(s[8], s[9]), u5 = pack2(s[10], s[11]);
      unsigned u6 = pack2(s[12], s[13]), u7 = pack2(s[14], s[15]);
      pl32swap(u0, u2); pl32swap(u1, u3); pl32swap(u4, u6); pl32swap(u5, u7);
      qbA[qt][0] = u0; qbA[qt][1] = u1; qbA[qt][2] = u2; qbA[qt][3] = u3;
      qbB[qt][0] = u4; qbB[qt][1] = u5; qbB[qt][2] = u6; qbB[qt][3] = u7;
    }
  }

  // ---- flash loop: 8 key-blocks of 32; no LDS writes, no barriers ----
  f32x16 acc0, acc1;
#pragma unroll
  for (int i = 0; i < 16; ++i) { acc0[i] = 0.f; acc1[i] = 0.f; }
  float z0 = 0.f, z1 = 0.f;
  const char* Kb = ws + WS_KIMG + (size_t)(b * 8 + h) * 16384;
  const char* Vb = ws + WS_VT + (size_t)(b * 8 + h) * 16384;
#pragma unroll 2
  for (int kb = 0; kb < 8; ++kb) {
    const char* kp = Kb + (kb * 32 + cl) * 64 + hb * 16;
    bf16x8 kf0 = *(const bf16x8*)kp;
    bf16x8 kf1 = *(const bf16x8*)(kp + 32);
    const char* vp = Vb + cl * 512 + kb * 64 + hb * 16;
    bf16x8 vf0 = *(const bf16x8*)vp;
    bf16x8 vf1 = *(const bf16x8*)(vp + 32);
    f32x16 bfr;
    {
      f32x4 b0 = *(const f32x4*)(bias_s + kb * 32 + hb * 4);
      f32x4 b1v = *(const f32x4*)(bias_s + kb * 32 + 8 + hb * 4);
      f32x4 b2v = *(const f32x4*)(bias_s + kb * 32 + 16 + hb * 4);
      f32x4 b3v = *(const f32x4*)(bias_s + kb * 32 + 24 + hb * 4);
      bfr[0] = b0[0]; bfr[1] = b0[1]; bfr[2] = b0[2]; bfr[3] = b0[3];
      bfr[4] = b1v[0]; bfr[5] = b1v[1]; bfr[6] = b1v[2]; bfr[7] = b1v[3];
      bfr[8] = b2v[0]; bfr[9] = b2v[1]; bfr[10] = b2v[2]; bfr[11] = b2v[3];
      bfr[12] = b3v[0]; bfr[13] = b3v[1]; bfr[14] = b3v[2]; bfr[15] = b3v[3];
    }
    // ---- qt = 0 ----
    {
      f32x16 s = __builtin_amdgcn_mfma_f32_32x32x16_bf16(kf0, __builtin_bit_cast(bf16x8, qbA[0]), bfr, 0, 0, 0);
      s = __builtin_amdgcn_mfma_f32_32x32x16_bf16(kf1, __builtin_bit_cast(bf16x8, qbB[0]), s, 0, 0, 0);
      float e[16];
#pragma unroll
      for (int i = 0; i < 16; ++i) e[i] = exp2f(s[i]);
#pragma unroll
      for (int i = 0; i < 16; ++i) z0 += e[i];
      unsigned u0 = pack2(e[0], e[1]), u1 = pack2(e[2], e[3]);
      unsigned u2 = pack2(e[4], e[5]), u3 = pack2(e[6], e[7]);
      unsigned u4 = pack2(e[8], e[9]), u5 = pack2(e[10], e[11]);
      unsigned u6 = pack2(e[12], e[13]), u7 = pack2(e[14], e[15]);
      pl32swap(u0, u2); pl32swap(u1, u3); pl32swap(u4, u6); pl32swap(u5, u7);
      u32x4 plo, phi;
      plo[0] = u0; plo[1] = u1; plo[2] = u2; plo[3] = u3;
      phi[0] = u4; phi[1] = u5; phi[2] = u6; phi[3] = u7;
      acc0 = __builtin_amdgcn_mfma_f32_32x32x16_bf16(vf0, __builtin_bit_cast(bf16x8, plo), acc0, 0, 0, 0);
      acc0 = __builtin_amdgcn_mfma_f32_32x32x16_bf16(vf1, __builtin_bit_cast(bf16x8, phi), acc0, 0, 0, 0);
    }
    // ---- qt = 1 ----
    {
      f32x16 s = __builtin_amdgcn_mfma_f32_32x32x16_bf16(kf0, __builtin_bit_cast(bf16x8, qbA[1]), bfr, 0, 0, 0);
      s = __builtin_amdgcn_mfma_f32_32x32x16_bf16(kf1, __builtin_bit_cast(bf16x8, qbB[1]), s, 0, 0, 0);
      float e[16];
#pragma unroll
      for (int i = 0; i < 16; ++i) e[i] = exp2f(s[i]);
#pragma unroll
      for (int i = 0; i < 16; ++i) z1 += e[i];
      unsigned u0 = pack2(e[0], e[1]), u1 = pack2(e[2], e[3]);
      unsigned u2 = pack2(e[4], e[5]), u3 = pack2(e[6], e[7]);
      unsigned u4 = pack2(e[8], e[9]), u5 = pack2(e[10], e[11]);
      unsigned u6 = pack2(e[12], e[13]), u7 = pack2(e[14], e[15]);
      pl32swap(u0, u2); pl32swap(u1, u3); pl32swap(u4, u6); pl32swap(u5, u7);
      u32x4 plo, phi;
      plo[0] = u0; plo[1] = u1; plo[2] = u2; plo[3] = u3;
      phi[0] = u4; phi[1] = u5; phi[2] = u6; phi[3] = u7;
      acc1 = __builtin_amdgcn_mfma_f32_32x32x16_bf16(vf0, __builtin_bit_cast(bf16x8, plo), acc1, 0, 0, 0);
      acc1 = __builtin_amdgcn_mfma_f32_32x32x16_bf16(vf1, __builtin_bit_cast(bf16x8, phi), acc1, 0, 0, 0);
    }
  }

  // ---- epilogue: Z cross-half reduce; scale; bf16 ctx -> d_out high halves
  z0 += __shfl_xor(z0, 32);
  z1 += __shfl_xor(z1, 32);
  float rz0 = 1.f / z0, rz1 = 1.f / z1;
  size_t rowbase = (size_t)(b * NP + p) * 256 + lq * 64;
#pragma unroll
  for (int qt = 0; qt < 2; ++qt) {
    const f32x16& a = qt ? acc1 : acc0;
    float rz = qt ? rz1 : rz0;
    char* po = (char*)outp + (rowbase + qt * 32 + cl) * 1024 + 512 + h * 64 + hb * 8;
#pragma unroll
    for (int g = 0; g < 4; ++g) {
      u32x2 o;
      o[0] = pack2(a[4 * g + 0] * rz, a[4 * g + 1] * rz);
      o[1] = pack2(a[4 * g + 2] * rz, a[4 * g + 3] * rz);
      *(u32x2*)(po + g * 16) = o;  // d = g*8 + 4*hb
    }
  }
}

// ---------------------------------------------------------------------------
// oproj: MFMA, in-place per 64-row block (reads own rows' bf16 ctx, writes
// same rows fp32). B-frags from woT image in L2.
// ---------------------------------------------------------------------------
__global__ __launch_bounds__(256) void oproj_kernel(
    const float* __restrict__ bo, const char* __restrict__ ws,
    float* __restrict__ outp) {
  __shared__ __align__(16) char Alds[32768];
  int t = threadIdx.x;
  int r0 = blockIdx.x * 64;
  {
    int row = t >> 2;
    const char* src = (const char*)outp + (size_t)(r0 + row) * 1024 + 512 + (t & 3) * 128;
#pragma unroll
    for (int u = 0; u < 8; ++u) {
      int c = (t & 3) * 8 + u;
      u32x4 v = *(const u32x4*)(src + u * 16);
      *(u32x4*)(Alds + fqs(row, c & 3, c >> 2, 4096)) = v;
    }
  }
  __syncthreads();
  int lane = t & 63, w = t >> 6, lo = lane & 15, hi = lane >> 4;
  f32x4 acc[4][4];
#pragma unroll
  for (int rt = 0; rt < 4; ++rt)
#pragma unroll
    for (int nt = 0; nt < 4; ++nt) acc[rt][nt] = zero4();
  const char* woT = ws + WS_WOT;
#pragma unroll
  for (int kt = 0; kt < 8; ++kt) {
    bf16x8 af[4];
#pragma unroll
    for (int rt = 0; rt < 4; ++rt)
      af[rt] = *(const bf16x8*)(Alds + fqs(rt * 16 + lo, hi, kt, 4096));
#pragma unroll
    for (int nt = 0; nt < 4; ++nt) {
      int j = (w * 4 + nt) * 16 + lo;
      bf16x8 bf = *(const bf16x8*)(woT + j * 512 + (kt * 32 + hi * 8) * 2);
#pragma unroll
      for (int rt = 0; rt < 4; ++rt)
        acc[rt][nt] = __builtin_amdgcn_mfma_f32_16x16x32_bf16(af[rt], bf, acc[rt][nt], 0, 0, 0);
    }
  }
#pragma unroll
  for (int nt = 0; nt < 4; ++nt) {
    int j = (w * 4 + nt) * 16 + lo;
    float boj = bo[j];
#pragma unroll
    for (int rt = 0; rt < 4; ++rt)
#pragma unroll
      for (int i = 0; i < 4; ++i)
        outp[(size_t)(r0 + rt * 16 + hi * 4 + i) * 256 + j] = acc[rt][nt][i] + boj;
  }
}

// ---------------------------------------------------------------------------
extern "C" void kernel_launch(void* const* d_in, const int* in_sizes, int n_in,
                              void* d_out, int out_size, void* d_ws, size_t ws_size,
                              hipStream_t stream) {
  const float* ehr = (const float*)d_in[0];
  const float* ehr_times = (const float*)d_in[1];
  const float* itv = (const float*)d_in[2];
  const float* w1 = (const float*)d_in[3];
  const float* b1 = (const float*)d_in[4];
  const float* w2 = (const float*)d_in[5];
  const float* b2 = (const float*)d_in[6];
  const float* wq = (const float*)d_in[7];
  const float* bq = (const float*)d_in[8];
  const float* wk = (const float*)d_in[9];
  const float* bk = (const float*)d_in[10];
  const float* wv = (const float*)d_in[11];
  const float* bv = (const float*)d_in[12];
  const float* wo = (const float*)d_in[13];
  const float* bo = (const float*)d_in[14];
  float* out = (float*)d_out;
  char* ws = (char*)d_ws;

  prep_kernel<<<225, 256, 0, stream>>>(w2, b2, wq, bq, wk, wv, wo, ws);
  kv_kernel<<<64, 256, 0, stream>>>(ehr, bk, bv, ws);
  attn_kernel<<<NB * NP * 4, 512, 0, stream>>>(ehr_times, itv, w1, b1, ws, out);
  oproj_kernel<<<512, 256, 0, stream>>>(bo, ws, out);
}